// Round 1
// baseline (7688.120 us; speedup 1.0000x reference)
//
#include <hip/hip_runtime.h>
#include <stdint.h>

// ---------- types ----------
typedef short short8v __attribute__((ext_vector_type(8)));
typedef float f32x4  __attribute__((ext_vector_type(4)));

#define TT 256
#define BB 64
#define HHH 1024
#define GG3 3072

__device__ inline uint16_t f2bf(float f){
  uint32_t u = __float_as_uint(f);
  uint32_t r = (u + 0x7fffu + ((u >> 16) & 1u)) >> 16;
  return (uint16_t)r;
}
__device__ inline float bf2f(uint16_t h){
  return __uint_as_float(((uint32_t)h) << 16);
}

// ---------- f32 -> bf16 conversion (vectorized) ----------
__global__ void cvt_f32_bf16(const float* __restrict__ src, uint16_t* __restrict__ dst, int n4){
  int i = blockIdx.x * blockDim.x + threadIdx.x;
  int stride = gridDim.x * blockDim.x;
  for (; i < n4; i += stride){
    float4 v = ((const float4*)src)[i];
    uint64_t p = (uint64_t)f2bf(v.x)
               | ((uint64_t)f2bf(v.y) << 16)
               | ((uint64_t)f2bf(v.z) << 32)
               | ((uint64_t)f2bf(v.w) << 48);
    ((uint64_t*)dst)[i] = p;
  }
}

// ---------- bf16 GEMM: C[m,n] = sum_k A[m,k] * Bw[n,k] + bias[n]  (C bf16) ----------
// m97-style: 128x128 tile, BK=64, 4 waves (64x64 each), global_load_lds staging.
#define GL2LDS(g, l) __builtin_amdgcn_global_load_lds((const __attribute__((address_space(1))) unsigned int*)(g), (__attribute__((address_space(3))) unsigned int*)(l), 16, 0, 0)

__global__ __launch_bounds__(256) void gemm_bt_bias(
    const uint16_t* __restrict__ A, const uint16_t* __restrict__ Bw,
    const float* __restrict__ bias, uint16_t* __restrict__ C,
    int M, int N, int K)
{
  __shared__ uint16_t As[128 * 64];
  __shared__ uint16_t Bs[128 * 64];
  const int tid  = threadIdx.x;
  const int lane = tid & 63, wid = tid >> 6;
  const int n0 = blockIdx.x * 128, m0 = blockIdx.y * 128;
  const int wrow = (wid & 1) * 64, wcol = (wid >> 1) * 64;
  const int l15 = lane & 15, l4 = lane >> 4;
  const int srow = lane >> 3, scol = (lane & 7) * 8;
  const size_t Ks = (size_t)K;

  f32x4 acc[4][4] = {};

  for (int kt = 0; kt < K; kt += 64){
    __syncthreads();
    const uint16_t* gA = A  + (size_t)m0 * Ks + kt;
    const uint16_t* gB = Bw + (size_t)n0 * Ks + kt;
    #pragma unroll
    for (int i = 0; i < 4; ++i){
      int rb = wid * 32 + i * 8;
      GL2LDS(gA + (size_t)(rb + srow) * Ks + scol, &As[rb * 64]);
      GL2LDS(gB + (size_t)(rb + srow) * Ks + scol, &Bs[rb * 64]);
    }
    __syncthreads();
    #pragma unroll
    for (int kk = 0; kk < 2; ++kk){
      short8v a[4], b[4];
      int koff = kk * 32 + l4 * 8;
      #pragma unroll
      for (int mt = 0; mt < 4; ++mt) a[mt] = *(const short8v*)&As[(wrow + mt*16 + l15) * 64 + koff];
      #pragma unroll
      for (int nt = 0; nt < 4; ++nt) b[nt] = *(const short8v*)&Bs[(wcol + nt*16 + l15) * 64 + koff];
      #pragma unroll
      for (int mt = 0; mt < 4; ++mt)
        #pragma unroll
        for (int nt = 0; nt < 4; ++nt)
          acc[mt][nt] = __builtin_amdgcn_mfma_f32_16x16x32_bf16(a[mt], b[nt], acc[mt][nt], 0, 0, 0);
    }
  }
  // epilogue: bias + bf16 store
  #pragma unroll
  for (int mt = 0; mt < 4; ++mt)
    #pragma unroll
    for (int nt = 0; nt < 4; ++nt){
      int col = n0 + wcol + nt * 16 + l15;
      float bv = bias[col];
      int rbase = m0 + wrow + mt * 16 + l4 * 4;
      #pragma unroll
      for (int j = 0; j < 4; ++j)
        C[(size_t)(rbase + j) * (size_t)N + col] = f2bf(acc[mt][nt][j] + bv);
    }
}

// ---------- grid barrier (monotonic counter, agent scope) ----------
__device__ inline void gridbar(unsigned* ctr, unsigned target){
  __syncthreads();
  if (threadIdx.x == 0){
    __hip_atomic_fetch_add(ctr, 1u, __ATOMIC_ACQ_REL, __HIP_MEMORY_SCOPE_AGENT);
    while (__hip_atomic_load(ctr, __ATOMIC_ACQUIRE, __HIP_MEMORY_SCOPE_AGENT) < target)
      __builtin_amdgcn_s_sleep(1);
  }
  __syncthreads();
}

// LDS reduce buffer index with XOR swizzle (keeps f32x4 alignment)
__device__ inline int ridx(int w, int c, int m){
  return (w * 48 + c) * 68 + (m ^ ((c & 7) << 2));
}

// ---------- persistent bidirectional GRU layer ----------
// grid = 128 blocks: dir = blk>>6 (0 fwd, 1 bwd), columns c0 = (blk&63)*16 of H.
// U fragments register-resident; h read direct from L2; waves K-split + LDS reduce.
__global__ __launch_bounds__(256, 1) void gru_layer(
    const uint16_t* __restrict__ xp,   // (T,B,3H) bf16 (bias already added)
    const uint16_t* __restrict__ U,    // (3H, H) bf16, rows: Ur | Uz | Un
    const float* __restrict__ bn,      // (H)
    uint16_t* __restrict__ hbuf,       // [2 parity][2 dir][64][1024] bf16
    float* __restrict__ hf32,          // [2 parity][2 dir][64][1024] f32
    uint16_t* __restrict__ out_bf,     // (T,B,2H) bf16 or null
    float* __restrict__ out_f32,       // (T,B,2H) f32 or null
    float* __restrict__ hid,           // 2 slots of (64,1024) f32: fwd then bwd
    unsigned* __restrict__ ctr)
{
  __shared__ float red[4 * 48 * 68];
  const int tid  = threadIdx.x;
  const int lane = tid & 63, wid = tid >> 6;
  const int dir  = blockIdx.x >> 6;
  const int c0   = (blockIdx.x & 63) * 16;
  const int l15 = lane & 15, l4 = lane >> 4;
  const int wk0 = wid * 256;

  // load register-resident B fragments (U weights), reused for all 256 steps
  short8v bfr[3][8];
  #pragma unroll
  for (int g = 0; g < 3; ++g)
    #pragma unroll
    for (int k32 = 0; k32 < 8; ++k32){
      int row = g * 1024 + c0 + l15;
      int k   = wk0 + k32 * 32 + l4 * 8;
      bfr[g][k32] = *(const short8v*)&U[(size_t)row * 1024 + k];
    }

  const int cc = tid & 15, mg = tid >> 4;
  // zero-init h (parity 0) for our columns
  {
    size_t base = (size_t)(0 * 2 + dir) * (64 * 1024);
    #pragma unroll
    for (int j = 0; j < 4; ++j){
      int m = mg * 4 + j;
      hbuf[base + (size_t)m * 1024 + c0 + cc] = 0;
      hf32[base + (size_t)m * 1024 + c0 + cc] = 0.f;
    }
  }
  gridbar(ctr, 128u);

  const float bnv = bn[c0 + cc];

  for (int s = 0; s < 256; ++s){
    const int par = s & 1;
    const int t = dir ? (255 - s) : s;
    const uint16_t* hb = hbuf + (size_t)(par * 2 + dir) * (64 * 1024);

    f32x4 acc[3][4] = {};
    #pragma unroll
    for (int k32 = 0; k32 < 8; ++k32){
      short8v af[4];
      int k = wk0 + k32 * 32 + l4 * 8;
      #pragma unroll
      for (int mt = 0; mt < 4; ++mt)
        af[mt] = *(const short8v*)&hb[(size_t)(mt * 16 + l15) * 1024 + k];
      #pragma unroll
      for (int g = 0; g < 3; ++g)
        #pragma unroll
        for (int mt = 0; mt < 4; ++mt)
          acc[g][mt] = __builtin_amdgcn_mfma_f32_16x16x32_bf16(af[mt], bfr[g][k32], acc[g][mt], 0, 0, 0);
    }

    // write partial sums to LDS (m-contiguous, swizzled)
    #pragma unroll
    for (int g = 0; g < 3; ++g)
      #pragma unroll
      for (int mt = 0; mt < 4; ++mt){
        int c48 = g * 16 + l15;
        int m   = mt * 16 + l4 * 4;
        *(f32x4*)&red[ridx(wid, c48, m)] = acc[g][mt];
      }
    __syncthreads();

    // reduce over 4 waves + gate elementwise; thread -> (col cc, rows mg*4..+3)
    f32x4 ra = {}, za = {}, na = {};
    #pragma unroll
    for (int w = 0; w < 4; ++w){
      ra += *(const f32x4*)&red[ridx(w, cc,       mg * 4)];
      za += *(const f32x4*)&red[ridx(w, 16 + cc,  mg * 4)];
      na += *(const f32x4*)&red[ridx(w, 32 + cc,  mg * 4)];
    }

    const size_t hwr = (size_t)((par ^ 1) * 2 + dir) * (64 * 1024);
    const size_t hrd = (size_t)(par * 2 + dir) * (64 * 1024);
    #pragma unroll
    for (int j = 0; j < 4; ++j){
      int m = mg * 4 + j;
      size_t xbase = ((size_t)t * 64 + m) * 3072 + c0 + cc;
      float xr = bf2f(xp[xbase]);
      float xz = bf2f(xp[xbase + 1024]);
      float xn = bf2f(xp[xbase + 2048]);
      float hold = hf32[hrd + (size_t)m * 1024 + c0 + cc];
      float r = 1.f / (1.f + __expf(-(xr + ra[j])));
      float z = 1.f / (1.f + __expf(-(xz + za[j])));
      float n = tanhf(xn + r * (na[j] + bnv));
      float hn = (1.f - z) * n + z * hold;
      hf32[hwr + (size_t)m * 1024 + c0 + cc] = hn;
      hbuf[hwr + (size_t)m * 1024 + c0 + cc] = f2bf(hn);
      size_t obase = ((size_t)t * 64 + m) * 2048 + (size_t)dir * 1024 + c0 + cc;
      if (out_bf) out_bf[obase] = f2bf(hn);
      else        out_f32[obase] = hn;
      if (s == 255) hid[((size_t)dir * 64 + m) * 1024 + c0 + cc] = hn;
    }
    if (s < 255) gridbar(ctr, 128u * (unsigned)(s + 2));
  }
}

// ---------- host ----------
extern "C" void kernel_launch(void* const* d_in, const int* in_sizes, int n_in,
                              void* d_out, int out_size, void* d_ws, size_t ws_size,
                              hipStream_t stream) {
  const float* x   = (const float*)d_in[0];
  const float* W0  = (const float*)d_in[1];
  const float* b0  = (const float*)d_in[2];
  const float* Ur0 = (const float*)d_in[3];
  const float* Uz0 = (const float*)d_in[4];
  const float* Un0 = (const float*)d_in[5];
  const float* bn0 = (const float*)d_in[6];
  const float* W1  = (const float*)d_in[7];
  const float* b1  = (const float*)d_in[8];
  const float* Ur1 = (const float*)d_in[9];
  const float* Uz1 = (const float*)d_in[10];
  const float* Un1 = (const float*)d_in[11];
  const float* bn1 = (const float*)d_in[12];
  float* out = (float*)d_out;

  char* base = (char*)d_ws;
  unsigned* ctr0 = (unsigned*)base;
  unsigned* ctr1 = (unsigned*)(base + 64);
  uint16_t* xb    = (uint16_t*)(base + 256);
  uint16_t* w0b   = xb    + (size_t)16384 * 1024;
  uint16_t* u0b   = w0b   + (size_t)3072 * 1024;
  uint16_t* w1b   = u0b   + (size_t)3072 * 1024;
  uint16_t* u1b   = w1b   + (size_t)3072 * 2048;
  uint16_t* xp    = u1b   + (size_t)3072 * 1024;
  uint16_t* out0b = xp    + (size_t)16384 * 3072;
  uint16_t* hbuf  = out0b + (size_t)16384 * 2048;
  float*    hf32  = (float*)(hbuf + (size_t)4 * 64 * 1024);

  hipMemsetAsync(d_ws, 0, 256, stream);

  // conversions to bf16
  auto cvt = [&](const float* s, uint16_t* d, size_t n){
    int n4 = (int)(n / 4);
    int grid = (n4 + 255) / 256; if (grid > 2048) grid = 2048;
    hipLaunchKernelGGL(cvt_f32_bf16, dim3(grid), dim3(256), 0, stream, s, d, n4);
  };
  cvt(x,   xb,  (size_t)16384 * 1024);
  cvt(W0,  w0b, (size_t)3072 * 1024);
  cvt(Ur0, u0b + 0 * (size_t)1024 * 1024, (size_t)1024 * 1024);
  cvt(Uz0, u0b + 1 * (size_t)1024 * 1024, (size_t)1024 * 1024);
  cvt(Un0, u0b + 2 * (size_t)1024 * 1024, (size_t)1024 * 1024);
  cvt(W1,  w1b, (size_t)3072 * 2048);
  cvt(Ur1, u1b + 0 * (size_t)1024 * 1024, (size_t)1024 * 1024);
  cvt(Uz1, u1b + 1 * (size_t)1024 * 1024, (size_t)1024 * 1024);
  cvt(Un1, u1b + 2 * (size_t)1024 * 1024, (size_t)1024 * 1024);

  // layer 0: xp0 = x @ W0^T + b0
  hipLaunchKernelGGL(gemm_bt_bias, dim3(24, 128), dim3(256), 0, stream,
                     xb, w0b, b0, xp, 16384, 3072, 1024);
  // layer 0 recurrence -> out0b (bf16), hidden slots 0,1
  hipLaunchKernelGGL(gru_layer, dim3(128), dim3(256), 0, stream,
                     xp, u0b, bn0, hbuf, hf32,
                     out0b, (float*)nullptr,
                     out + (size_t)33554432, ctr0);
  // layer 1: xp1 = out0 @ W1^T + b1
  hipLaunchKernelGGL(gemm_bt_bias, dim3(24, 128), dim3(256), 0, stream,
                     out0b, w1b, b1, xp, 16384, 3072, 2048);
  // layer 1 recurrence -> d_out (f32), hidden slots 2,3
  hipLaunchKernelGGL(gru_layer, dim3(128), dim3(256), 0, stream,
                     xp, u1b, bn1, hbuf, hf32,
                     (uint16_t*)nullptr, out,
                     out + (size_t)33554432 + (size_t)2 * 64 * 1024, ctr1);
}

// Round 2
// 6241.260 us; speedup vs baseline: 1.2318x; 1.2318x over previous
//
#include <hip/hip_runtime.h>
#include <stdint.h>

// ---------- types ----------
typedef short short8v __attribute__((ext_vector_type(8)));
typedef float f32x4  __attribute__((ext_vector_type(4)));

__device__ inline uint16_t f2bf(float f){
  uint32_t u = __float_as_uint(f);
  uint32_t r = (u + 0x7fffu + ((u >> 16) & 1u)) >> 16;
  return (uint16_t)r;
}
__device__ inline float bf2f(uint16_t h){
  return __uint_as_float(((uint32_t)h) << 16);
}

// ---------- f32 -> bf16 conversion (vectorized) ----------
__global__ void cvt_f32_bf16(const float* __restrict__ src, uint16_t* __restrict__ dst, int n4){
  int i = blockIdx.x * blockDim.x + threadIdx.x;
  int stride = gridDim.x * blockDim.x;
  for (; i < n4; i += stride){
    float4 v = ((const float4*)src)[i];
    uint64_t p = (uint64_t)f2bf(v.x)
               | ((uint64_t)f2bf(v.y) << 16)
               | ((uint64_t)f2bf(v.z) << 32)
               | ((uint64_t)f2bf(v.w) << 48);
    ((uint64_t*)dst)[i] = p;
  }
}

// ---------- bf16 GEMM: C[m,n] = sum_k A[m,k] * Bw[n,k] + bias[n]  (C bf16) ----------
#define GL2LDS(g, l) __builtin_amdgcn_global_load_lds((const __attribute__((address_space(1))) unsigned int*)(g), (__attribute__((address_space(3))) unsigned int*)(l), 16, 0, 0)

__global__ __launch_bounds__(256) void gemm_bt_bias(
    const uint16_t* __restrict__ A, const uint16_t* __restrict__ Bw,
    const float* __restrict__ bias, uint16_t* __restrict__ C,
    int M, int N, int K)
{
  __shared__ uint16_t As[128 * 64];
  __shared__ uint16_t Bs[128 * 64];
  const int tid  = threadIdx.x;
  const int lane = tid & 63, wid = tid >> 6;
  const int n0 = blockIdx.x * 128, m0 = blockIdx.y * 128;
  const int wrow = (wid & 1) * 64, wcol = (wid >> 1) * 64;
  const int l15 = lane & 15, l4 = lane >> 4;
  const int srow = lane >> 3, scol = (lane & 7) * 8;
  const size_t Ks = (size_t)K;

  f32x4 acc[4][4] = {};

  for (int kt = 0; kt < K; kt += 64){
    __syncthreads();
    const uint16_t* gA = A  + (size_t)m0 * Ks + kt;
    const uint16_t* gB = Bw + (size_t)n0 * Ks + kt;
    #pragma unroll
    for (int i = 0; i < 4; ++i){
      int rb = wid * 32 + i * 8;
      GL2LDS(gA + (size_t)(rb + srow) * Ks + scol, &As[rb * 64]);
      GL2LDS(gB + (size_t)(rb + srow) * Ks + scol, &Bs[rb * 64]);
    }
    __syncthreads();
    #pragma unroll
    for (int kk = 0; kk < 2; ++kk){
      short8v a[4], b[4];
      int koff = kk * 32 + l4 * 8;
      #pragma unroll
      for (int mt = 0; mt < 4; ++mt) a[mt] = *(const short8v*)&As[(wrow + mt*16 + l15) * 64 + koff];
      #pragma unroll
      for (int nt = 0; nt < 4; ++nt) b[nt] = *(const short8v*)&Bs[(wcol + nt*16 + l15) * 64 + koff];
      #pragma unroll
      for (int mt = 0; mt < 4; ++mt)
        #pragma unroll
        for (int nt = 0; nt < 4; ++nt)
          acc[mt][nt] = __builtin_amdgcn_mfma_f32_16x16x32_bf16(a[mt], b[nt], acc[mt][nt], 0, 0, 0);
    }
  }
  #pragma unroll
  for (int mt = 0; mt < 4; ++mt)
    #pragma unroll
    for (int nt = 0; nt < 4; ++nt){
      int col = n0 + wcol + nt * 16 + l15;
      float bv = bias[col];
      int rbase = m0 + wrow + mt * 16 + l4 * 4;
      #pragma unroll
      for (int j = 0; j < 4; ++j)
        C[(size_t)(rbase + j) * (size_t)N + col] = f2bf(acc[mt][nt][j] + bv);
    }
}

// LDS reduce buffer index with XOR swizzle (keeps f32x4 alignment)
__device__ inline int ridx(int w, int c, int m){
  return (w * 48 + c) * 68 + (m ^ ((c & 7) << 2));
}

// ---------- persistent bidirectional GRU layer ----------
// grid = 128 blocks: dir = blk>>6 (0 fwd, 1 bwd), columns c0 = (blk&63)*16 of H.
// U fragments register-resident; h_old f32 in registers; flag-array barrier
// with relaxed agent polls + one release/acquire fence per step.
__global__ __launch_bounds__(256, 1) void gru_layer(
    const uint16_t* __restrict__ xp,   // (T,B,3H) bf16 (bias already added)
    const uint16_t* __restrict__ U,    // (3H, H) bf16, rows: Ur | Uz | Un
    const float* __restrict__ bn,      // (H)
    uint16_t* __restrict__ hbuf,       // [2 parity][2 dir][64][1024] bf16
    uint16_t* __restrict__ out_bf,     // (T,B,2H) bf16 or null
    float* __restrict__ out_f32,       // (T,B,2H) f32 or null
    float* __restrict__ hid,           // 2 slots of (64,1024) f32: fwd then bwd
    unsigned* __restrict__ flags)      // [2 dir][64] stride-4 u32 (16B apart)
{
  __shared__ float red[4 * 48 * 68];
  const int tid  = threadIdx.x;
  const int lane = tid & 63, wid = tid >> 6;
  const int dir  = blockIdx.x >> 6;
  const int blkc = blockIdx.x & 63;
  const int c0   = blkc * 16;
  const int l15 = lane & 15, l4 = lane >> 4;
  const int wk0 = wid * 256;
  unsigned* myflags = flags + dir * 256;   // 64 flags * 4 u32 stride = 1 KB

  // register-resident B fragments (U weights), reused for all 256 steps
  short8v bfr[3][8];
  #pragma unroll
  for (int g = 0; g < 3; ++g)
    #pragma unroll
    for (int k32 = 0; k32 < 8; ++k32){
      int row = g * 1024 + c0 + l15;
      int k   = wk0 + k32 * 32 + l4 * 8;
      bfr[g][k32] = *(const short8v*)&U[(size_t)row * 1024 + k];
    }

  const int cc = tid & 15, mg = tid >> 4;
  float hold[4] = {0.f, 0.f, 0.f, 0.f};

  // zero-init h (parity 0) for our columns
  {
    size_t base = (size_t)dir * (64 * 1024);
    #pragma unroll
    for (int j = 0; j < 4; ++j)
      hbuf[base + (size_t)(mg * 4 + j) * 1024 + c0 + cc] = 0;
  }
  const float bnv = bn[c0 + cc];

  // prefetch xp for step 0
  uint16_t pxr[4], pxz[4], pxn[4];
  {
    int t0 = dir ? 255 : 0;
    #pragma unroll
    for (int j = 0; j < 4; ++j){
      size_t xb2 = ((size_t)t0 * 64 + mg * 4 + j) * 3072 + c0 + cc;
      pxr[j] = xp[xb2]; pxz[j] = xp[xb2 + 1024]; pxn[j] = xp[xb2 + 2048];
    }
  }

  __syncthreads();                         // drain init stores (per-wave vmcnt)
  if (tid == 0){
    __builtin_amdgcn_fence(__ATOMIC_RELEASE, "agent");
    __hip_atomic_store(&myflags[blkc * 4], 1u, __ATOMIC_RELAXED, __HIP_MEMORY_SCOPE_AGENT);
  }

  for (int s = 0; s < 256; ++s){
    const int par = s & 1;
    const int t = dir ? (255 - s) : s;

    // ---- wait: all blocks of this direction have finished step s-1 ----
    if (wid == 0){
      const unsigned tgt = (unsigned)(s + 1);
      int spins = 0;
      for (;;){
        unsigned v = __hip_atomic_load(&myflags[lane * 4], __ATOMIC_RELAXED, __HIP_MEMORY_SCOPE_AGENT);
        if (__all((int)(v >= tgt))) break;
        __builtin_amdgcn_s_sleep(1);
        if (((++spins) & 15) == 0)
          __builtin_amdgcn_fence(__ATOMIC_ACQUIRE, "agent");   // safety valve
      }
      __builtin_amdgcn_fence(__ATOMIC_ACQUIRE, "agent");
    }
    __syncthreads();

    const uint16_t* hb = hbuf + (size_t)(par * 2 + dir) * (64 * 1024);

    f32x4 acc[3][4] = {};
    #pragma unroll
    for (int k32 = 0; k32 < 8; ++k32){
      short8v af[4];
      int k = wk0 + k32 * 32 + l4 * 8;
      #pragma unroll
      for (int mt = 0; mt < 4; ++mt)
        af[mt] = *(const short8v*)&hb[(size_t)(mt * 16 + l15) * 1024 + k];
      #pragma unroll
      for (int g = 0; g < 3; ++g)
        #pragma unroll
        for (int mt = 0; mt < 4; ++mt)
          acc[g][mt] = __builtin_amdgcn_mfma_f32_16x16x32_bf16(af[mt], bfr[g][k32], acc[g][mt], 0, 0, 0);
    }

    // write partial sums to LDS (m-contiguous, swizzled)
    #pragma unroll
    for (int g = 0; g < 3; ++g)
      #pragma unroll
      for (int mt = 0; mt < 4; ++mt)
        *(f32x4*)&red[ridx(wid, g * 16 + l15, mt * 16 + l4 * 4)] = acc[g][mt];
    __syncthreads();

    // reduce over 4 waves; thread -> (col cc, rows mg*4..+3)
    f32x4 ra = {}, za = {}, na = {};
    #pragma unroll
    for (int w = 0; w < 4; ++w){
      ra += *(const f32x4*)&red[ridx(w, cc,      mg * 4)];
      za += *(const f32x4*)&red[ridx(w, 16 + cc, mg * 4)];
      na += *(const f32x4*)&red[ridx(w, 32 + cc, mg * 4)];
    }

    const size_t hwr = (size_t)((par ^ 1) * 2 + dir) * (64 * 1024);
    #pragma unroll
    for (int j = 0; j < 4; ++j){
      int m = mg * 4 + j;
      float r = 1.f / (1.f + __expf(-(bf2f(pxr[j]) + ra[j])));
      float z = 1.f / (1.f + __expf(-(bf2f(pxz[j]) + za[j])));
      float n = tanhf(bf2f(pxn[j]) + r * (na[j] + bnv));
      float hn = (1.f - z) * n + z * hold[j];
      hold[j] = hn;
      hbuf[hwr + (size_t)m * 1024 + c0 + cc] = f2bf(hn);
      size_t obase = ((size_t)t * 64 + m) * 2048 + (size_t)dir * 1024 + c0 + cc;
      if (out_bf) __builtin_nontemporal_store(f2bf(hn), &out_bf[obase]);
      else        __builtin_nontemporal_store(hn, &out_f32[obase]);
      if (s == 255) hid[((size_t)dir * 64 + m) * 1024 + c0 + cc] = hn;
    }
    __syncthreads();                       // drain h stores; red reuse safe

    if (s < 255){
      if (tid == 0){
        __builtin_amdgcn_fence(__ATOMIC_RELEASE, "agent");
        __hip_atomic_store(&myflags[blkc * 4], (unsigned)(s + 2), __ATOMIC_RELAXED, __HIP_MEMORY_SCOPE_AGENT);
      }
      // prefetch next-step xp; overlaps with next poll wait
      int tn = dir ? (255 - (s + 1)) : (s + 1);
      #pragma unroll
      for (int j = 0; j < 4; ++j){
        size_t xb2 = ((size_t)tn * 64 + mg * 4 + j) * 3072 + c0 + cc;
        pxr[j] = xp[xb2]; pxz[j] = xp[xb2 + 1024]; pxn[j] = xp[xb2 + 2048];
      }
    }
  }
}

// ---------- host ----------
extern "C" void kernel_launch(void* const* d_in, const int* in_sizes, int n_in,
                              void* d_out, int out_size, void* d_ws, size_t ws_size,
                              hipStream_t stream) {
  const float* x   = (const float*)d_in[0];
  const float* W0  = (const float*)d_in[1];
  const float* b0  = (const float*)d_in[2];
  const float* Ur0 = (const float*)d_in[3];
  const float* Uz0 = (const float*)d_in[4];
  const float* Un0 = (const float*)d_in[5];
  const float* bn0 = (const float*)d_in[6];
  const float* W1  = (const float*)d_in[7];
  const float* b1  = (const float*)d_in[8];
  const float* Ur1 = (const float*)d_in[9];
  const float* Uz1 = (const float*)d_in[10];
  const float* Un1 = (const float*)d_in[11];
  const float* bn1 = (const float*)d_in[12];
  float* out = (float*)d_out;

  char* base = (char*)d_ws;
  unsigned* ctr0 = (unsigned*)base;                  // layer0 flags (2 dirs * 1KB)
  unsigned* ctr1 = (unsigned*)(base + 4096);         // layer1 flags
  uint16_t* xb    = (uint16_t*)(base + 8192);
  uint16_t* w0b   = xb    + (size_t)16384 * 1024;
  uint16_t* u0b   = w0b   + (size_t)3072 * 1024;
  uint16_t* w1b   = u0b   + (size_t)3072 * 1024;
  uint16_t* u1b   = w1b   + (size_t)3072 * 2048;
  uint16_t* xp    = u1b   + (size_t)3072 * 1024;
  uint16_t* out0b = xp    + (size_t)16384 * 3072;
  uint16_t* hbuf  = out0b + (size_t)16384 * 2048;

  hipMemsetAsync(d_ws, 0, 8192, stream);

  auto cvt = [&](const float* s, uint16_t* d, size_t n){
    int n4 = (int)(n / 4);
    int grid = (n4 + 255) / 256; if (grid > 2048) grid = 2048;
    hipLaunchKernelGGL(cvt_f32_bf16, dim3(grid), dim3(256), 0, stream, s, d, n4);
  };
  cvt(x,   xb,  (size_t)16384 * 1024);
  cvt(W0,  w0b, (size_t)3072 * 1024);
  cvt(Ur0, u0b + 0 * (size_t)1024 * 1024, (size_t)1024 * 1024);
  cvt(Uz0, u0b + 1 * (size_t)1024 * 1024, (size_t)1024 * 1024);
  cvt(Un0, u0b + 2 * (size_t)1024 * 1024, (size_t)1024 * 1024);
  cvt(W1,  w1b, (size_t)3072 * 2048);
  cvt(Ur1, u1b + 0 * (size_t)1024 * 1024, (size_t)1024 * 1024);
  cvt(Uz1, u1b + 1 * (size_t)1024 * 1024, (size_t)1024 * 1024);
  cvt(Un1, u1b + 2 * (size_t)1024 * 1024, (size_t)1024 * 1024);

  // layer 0: xp0 = x @ W0^T + b0
  hipLaunchKernelGGL(gemm_bt_bias, dim3(24, 128), dim3(256), 0, stream,
                     xb, w0b, b0, xp, 16384, 3072, 1024);
  // layer 0 recurrence -> out0b (bf16), hidden slots 0,1
  hipLaunchKernelGGL(gru_layer, dim3(128), dim3(256), 0, stream,
                     xp, u0b, bn0, hbuf,
                     out0b, (float*)nullptr,
                     out + (size_t)33554432, ctr0);
  // layer 1: xp1 = out0 @ W1^T + b1
  hipLaunchKernelGGL(gemm_bt_bias, dim3(24, 128), dim3(256), 0, stream,
                     out0b, w1b, b1, xp, 16384, 3072, 2048);
  // layer 1 recurrence -> d_out (f32), hidden slots 2,3
  hipLaunchKernelGGL(gru_layer, dim3(128), dim3(256), 0, stream,
                     xp, u1b, bn1, hbuf,
                     (uint16_t*)nullptr, out,
                     out + (size_t)33554432 + (size_t)2 * 64 * 1024, ctr1);
}